// Round 4
// baseline (594.474 us; speedup 1.0000x reference)
//
#include <hip/hip_runtime.h>

// ---- shapes (hard-coded to this problem) ----
#define TT 64
#define SLOT 320          // OUT + ACT
#define CONCAT 1536       // IN + 4*SLOT
// sequential kernel: x rows hold z-history only (4 slots x 256)
#define ROWP2 1032        // 1024 + 8 pad shorts
#define XSH2 (16 * ROWP2)            // 16512 shorts = 33024 B
// ugemm staging row: 512 + 8 pad
#define XROW 520

typedef __attribute__((ext_vector_type(8))) short bf16x8;
typedef __attribute__((ext_vector_type(4))) short short4v;
typedef __attribute__((ext_vector_type(4))) float float4v;

__device__ __forceinline__ short f2bf(float f) {
    union { float f; unsigned u; } v;
    v.f = f;
    unsigned r = v.u + 0x7fffu + ((v.u >> 16) & 1u);  // RNE
    return (short)(r >> 16);
}

// Repack W (256 x 1536 fp32) into two bf16 MFMA-B-fragment streams:
//  Wzb  (idx < 32768):  [tl 0..15][kb 0..31][lane][8] over the 1024 z-history cols
//  Waob (idx >= 32768): [tl 0..15][kb 0..15][lane][8] over the 512 a-hist+o cols
// frag: lane L holds W[tl*16 + (L&15)][col(kb*32 + (L>>4)*8 + j)], j=0..7.
__global__ void wprep_kernel(const float* __restrict__ W, short* __restrict__ Wb) {
    int idx = blockIdx.x * 256 + threadIdx.x;       // 0 .. 49151
    if (idx >= 49152) return;
    int lane = idx & 63;
    int q = lane >> 4, ln = lane & 15;
    int n, col;
    short* dst;
    if (idx < 32768) {              // z-part
        int kb = (idx >> 6) & 31;
        int tl = idx >> 11;
        n = tl * 16 + ln;
        int kz = kb * 32 + q * 8;                   // 0..1023
        col = (kz >> 8) * SLOT + (kz & 255);        // slot h z-cols at h*320
        dst = Wb + (size_t)idx * 8;
    } else {                        // ao-part
        int idx3 = idx - 32768;
        int kb = (idx3 >> 6) & 15;
        int tl = idx3 >> 10;
        n = tl * 16 + ln;
        int ka = kb * 32 + q * 8;                   // 0..511
        col = (ka < 256) ? ((ka >> 6) * SLOT + 256 + (ka & 63))  // a-slot cols
                         : (1024 + ka);                          // o cols 1280..
        dst = Wb + (size_t)32768 * 8 + (size_t)idx3 * 8;
    }
    const float* src = W + (size_t)n * CONCAT + col;
    short4v s0, s1;
    s0.x = f2bf(src[0]); s0.y = f2bf(src[1]); s0.z = f2bf(src[2]); s0.w = f2bf(src[3]);
    s1.x = f2bf(src[4]); s1.y = f2bf(src[5]); s1.z = f2bf(src[6]); s1.w = f2bf(src[7]);
    *(short4v*)dst = s0;
    *(short4v*)(dst + 4) = s1;
}

// Parallel precompute: u = W_ao * [a_hist | o] + b for ALL 65536 tokens, written
// into out (sequential kernel reads u then overwrites with z in-place).
// Grid 1024 WGs (one per (b,t)) x 256 threads (4 waves). M=64 (the 64 p's),
// N=256, K=512, single LDS stage (a-slots and o are contiguous 16KB/64KB blocks).
__global__ __launch_bounds__(256) void ugemm_kernel(
    const float* __restrict__ o,    // (B,T,P,256)
    const float* __restrict__ act,  // (B,T,P,64)
    const float* __restrict__ bias, // (256)
    const short* __restrict__ Wb,   // Wzb + Waob
    float* __restrict__ out)        // (B,T,P,256) <- u
{
    __shared__ short xp[64 * XROW];   // 66560 B

    const int tid = threadIdx.x;
    const int wg  = blockIdx.x;       // b = wg>>6, t = wg&63
    const int b   = wg >> 6, t = wg & 63;
    const size_t tau0 = (size_t)wg * 64;

    // stage a_hist slots: slot h holds a(t-4+h); each slot = contiguous 16KB
#pragma unroll
    for (int h = 0; h < 4; ++h) {
        int tp = t - 4 + h;
        const float* ap = act + (((size_t)b * 64 + tp) * 64) * 64;
        for (int f = tid; f < 1024; f += 256) {       // 1024 float4 / slot
            int p = f >> 4, c4 = (f & 15) << 2;
            short4v s;
            if (tp >= 0) {
                float4v v = *(const float4v*)(ap + p * 64 + c4);
                s.x = f2bf(v.x); s.y = f2bf(v.y); s.z = f2bf(v.z); s.w = f2bf(v.w);
            } else { s.x = 0; s.y = 0; s.z = 0; s.w = 0; }
            *(short4v*)&xp[p * XROW + h * 64 + c4] = s;
        }
    }
    // stage o: one contiguous 64KB block
    {
        const float* op = o + tau0 * 256;
        for (int f = tid; f < 4096; f += 256) {       // 4096 float4
            int p = f >> 6, c4 = (f & 63) << 2;
            float4v v = *(const float4v*)(op + p * 256 + c4);
            short4v s;
            s.x = f2bf(v.x); s.y = f2bf(v.y); s.z = f2bf(v.z); s.w = f2bf(v.w);
            *(short4v*)&xp[p * XROW + 256 + c4] = s;
        }
    }
    __syncthreads();

    const int wv = tid >> 6, lane = tid & 63, q = lane >> 4, ln = lane & 15;
    const short* wao = Wb + 262144;   // Waob shorts offset

    float4v acc[4][4];                // [m][i], all static-indexed
#pragma unroll
    for (int m = 0; m < 4; ++m)
#pragma unroll
        for (int i = 0; i < 4; ++i)
            acc[m][i] = (float4v){0.f, 0.f, 0.f, 0.f};

#pragma unroll
    for (int kb = 0; kb < 16; ++kb) {
        bf16x8 bf[4];
#pragma unroll
        for (int i = 0; i < 4; ++i)
            bf[i] = *(const bf16x8*)(wao + (((size_t)(4 * wv + i) * 16 + kb) * 64 + lane) * 8);
#pragma unroll
        for (int m = 0; m < 4; ++m) {
            bf16x8 af = *(const bf16x8*)&xp[(m * 16 + ln) * XROW + kb * 32 + q * 8];
#pragma unroll
            for (int i = 0; i < 4; ++i)
                acc[m][i] = __builtin_amdgcn_mfma_f32_16x16x32_bf16(af, bf[i], acc[m][i], 0, 0, 0);
        }
    }

#pragma unroll
    for (int i = 0; i < 4; ++i) {
        float bv = bias[(4 * wv + i) * 16 + ln];
#pragma unroll
        for (int m = 0; m < 4; ++m)
#pragma unroll
            for (int r = 0; r < 4; ++r)
                out[(tau0 + m * 16 + q * 4 + r) * 256 + (4 * wv + i) * 16 + ln] = acc[m][i][r] + bv;
    }
}

// Sequential kernel. 64 WGs x 1024 threads (16 waves), 16 seqs/WG.
// W_z (256x1024 bf16 = 512KB) is ENTIRELY VGPR-RESIDENT across the CU:
// wave (c = w&3, g = w>>2) holds tiles 4c..4c+3 x kbs 8g..8g+7 = 32 frags
// = 128 VGPRs, loaded once before the t-loop. Per step: 8 LDS A-reads +
// 32 MFMAs per wave, K-reduce via LDS scratch, NO global W traffic.
// u(t) (incl. bias) is read from out[tok] and overwritten with z in-place.
__global__ __launch_bounds__(1024) void hist_kernel(
    const short* __restrict__ Wzb,  // packed bf16 Wz frags
    float* __restrict__ out)        // in: u; out: z
{
    __shared__ short lds[XSH2 + 32768];   // 33024 + 65536 = 98560 B

    const int tid  = threadIdx.x;
    const int wave = tid >> 6;
    const int lane = tid & 63;
    const int q    = lane >> 4;
    const int ln   = lane & 15;
    const int bb   = blockIdx.x >> 2;
    const int p0   = (blockIdx.x & 3) << 4;

    const int c = wave & 3;      // out-column group -> tiles 4c..4c+3
    const int g = wave >> 2;     // K-group -> logical kbs 8g..8g+7 (= z-slot g)

    float* scr = (float*)&lds[XSH2];   // [tile 16][g 4][lane 64][4 f32]

    // zero z history (16 rows x 1024 bf16)
    for (int i = tid; i < 8192; i += 1024) {
        int row = i >> 9, cc = i & 511;
        *(float*)&lds[row * ROWP2 + cc * 2] = 0.f;
    }

    const int arow = ln * ROWP2 + (q << 3);

    // resident Wz frags: [i][j] = tile 4c+i, kb 8g+j  (128 VGPRs)
    const short* wp = Wzb + ((size_t)(4 * c * 32 + 8 * g) * 64 + lane) * 8;
    bf16x8 wres[4][8];
#pragma unroll
    for (int i = 0; i < 4; ++i)
#pragma unroll
        for (int j = 0; j < 8; ++j)
            wres[i][j] = *(const bf16x8*)(wp + (size_t)(i * 32 + j) * 512);

    for (int t = 0; t < TT; ++t) {
        const size_t tok = ((size_t)bb * TT + t) * 64 + p0;
        float* outp = out + tok * 256;
        const int n = (wave << 4) + ln;

        // prefetch u (this wave's 4 outputs; latency covered by MFMA phase)
        float u0 = outp[((q << 2) + 0) * 256 + n];
        float u1 = outp[((q << 2) + 1) * 256 + n];
        float u2 = outp[((q << 2) + 2) * 256 + n];
        float u3 = outp[((q << 2) + 3) * 256 + n];

        __syncthreads();   // alpha: prev-step z history writes visible

        const int ps = ((g + t) & 3) << 8;   // physical slot base (256 shorts/slot)
        float4v acc0 = {0.f, 0.f, 0.f, 0.f};
        float4v acc1 = acc0, acc2 = acc0, acc3 = acc0;
#pragma unroll
        for (int j = 0; j < 8; ++j) {
            bf16x8 af = *(const bf16x8*)&lds[arow + ps + j * 32];
            acc0 = __builtin_amdgcn_mfma_f32_16x16x32_bf16(af, wres[0][j], acc0, 0, 0, 0);
            acc1 = __builtin_amdgcn_mfma_f32_16x16x32_bf16(af, wres[1][j], acc1, 0, 0, 0);
            acc2 = __builtin_amdgcn_mfma_f32_16x16x32_bf16(af, wres[2][j], acc2, 0, 0, 0);
            acc3 = __builtin_amdgcn_mfma_f32_16x16x32_bf16(af, wres[3][j], acc3, 0, 0, 0);
        }

        // write K-partials: tile 4c+i, group g
        *(float4v*)&scr[(((4 * c + 0) * 4 + g) * 64 + lane) * 4] = acc0;
        *(float4v*)&scr[(((4 * c + 1) * 4 + g) * 64 + lane) * 4] = acc1;
        *(float4v*)&scr[(((4 * c + 2) * 4 + g) * 64 + lane) * 4] = acc2;
        *(float4v*)&scr[(((4 * c + 3) * 4 + g) * 64 + lane) * 4] = acc3;

        __syncthreads();   // gamma: partials visible; all A-reads done

        // wave w reduces tile w
        float4v s0 = *(const float4v*)&scr[((wave * 4 + 0) * 64 + lane) * 4];
        float4v s1 = *(const float4v*)&scr[((wave * 4 + 1) * 64 + lane) * 4];
        float4v s2 = *(const float4v*)&scr[((wave * 4 + 2) * 64 + lane) * 4];
        float4v s3 = *(const float4v*)&scr[((wave * 4 + 3) * 64 + lane) * 4];
        float4v zz = (s0 + s1) + (s2 + s3);

        // epilogue: z = reduce + u (bias already in u); store global + bf16 history
        const int pz = (t & 3) << 8;
        float z0 = zz[0] + u0, z1 = zz[1] + u1, z2 = zz[2] + u2, z3 = zz[3] + u3;
        outp[((q << 2) + 0) * 256 + n] = z0;
        outp[((q << 2) + 1) * 256 + n] = z1;
        outp[((q << 2) + 2) * 256 + n] = z2;
        outp[((q << 2) + 3) * 256 + n] = z3;
        lds[((q << 2) + 0) * ROWP2 + pz + n] = f2bf(z0);
        lds[((q << 2) + 1) * ROWP2 + pz + n] = f2bf(z1);
        lds[((q << 2) + 2) * ROWP2 + pz + n] = f2bf(z2);
        lds[((q << 2) + 3) * ROWP2 + pz + n] = f2bf(z3);
        // next iteration's barrier alpha orders these writes before next A-reads
    }
}

extern "C" void kernel_launch(void* const* d_in, const int* in_sizes, int n_in,
                              void* d_out, int out_size, void* d_ws, size_t ws_size,
                              hipStream_t stream) {
    const float* o  = (const float*)d_in[0];
    const float* a  = (const float*)d_in[1];
    const float* W  = (const float*)d_in[2];
    const float* b  = (const float*)d_in[3];
    short* Wb = (short*)d_ws;   // 786432 B used (Wzb 524288 + Waob 262144)

    hipLaunchKernelGGL(wprep_kernel, dim3(192), dim3(256), 0, stream, W, Wb);
    hipLaunchKernelGGL(ugemm_kernel, dim3(1024), dim3(256), 0, stream,
                       o, a, b, Wb, (float*)d_out);
    hipLaunchKernelGGL(hist_kernel, dim3(64), dim3(1024), 0, stream,
                       Wb, (float*)d_out);
}

// Round 5
// 468.752 us; speedup vs baseline: 1.2682x; 1.2682x over previous
//
#include <hip/hip_runtime.h>

// ---- shapes (hard-coded to this problem) ----
#define TT 64
#define SLOT 320          // OUT + ACT
#define CONCAT 1536       // IN + 4*SLOT
#define XROW 520          // ugemm staging row: 512 + 8 pad

typedef __attribute__((ext_vector_type(8))) short bf16x8;
typedef __attribute__((ext_vector_type(4))) short short4v;
typedef __attribute__((ext_vector_type(4))) float float4v;

// agent-scope (device) atomics: visible across XCDs without L2 coherence
#define AL(p)    __hip_atomic_load((p), __ATOMIC_RELAXED, __HIP_MEMORY_SCOPE_AGENT)
#define AS(p, v) __hip_atomic_store((p), (v), __ATOMIC_RELAXED, __HIP_MEMORY_SCOPE_AGENT)
#define SPIN_PAUSE __builtin_amdgcn_s_sleep(2)

__device__ __forceinline__ short f2bf(float f) {
    union { float f; unsigned u; } v;
    v.f = f;
    unsigned r = v.u + 0x7fffu + ((v.u >> 16) & 1u);  // RNE
    return (short)(r >> 16);
}

// Repack W (256 x 1536 fp32) into bf16 MFMA-B-fragment streams:
//  sec 0..3 (64K shorts each): tap h=sec+1 -> A_h = W[:, (3-sec)*320 .. +255]
//                              [tl 0..15][kb 0..7][lane][8]
//  Wao at short offset 262144: [tl 0..15][kb 0..15][lane][8] over a-hist+o cols
// frag: lane L holds W[tl*16 + (L&15)][colbase + kb*32 + (L>>4)*8 + j], j=0..7.
// Also resets the 1024 sync flags (runs before ugemm/hist on the same stream).
__global__ void wprep_kernel(const float* __restrict__ W, short* __restrict__ Wb,
                             unsigned* __restrict__ flags) {
    if (blockIdx.x == 0) {
        for (int i = threadIdx.x; i < 1024; i += 256) flags[i] = 0u;
    }
    int idx = blockIdx.x * 256 + threadIdx.x;       // 0 .. 49151
    if (idx >= 49152) return;
    int lane = idx & 63;
    int q = lane >> 4, ln = lane & 15;
    int n, col;
    if (idx < 32768) {              // tap sections
        int sec = idx >> 13;                        // 0..3
        int rem = idx & 8191;
        int tl = rem >> 9, kb = (rem >> 6) & 7;
        n = tl * 16 + ln;
        col = (3 - sec) * SLOT + kb * 32 + q * 8;   // A_1 at 960, A_4 at 0
    } else {                        // ao-part (for ugemm)
        int idx3 = idx - 32768;
        int tl = idx3 >> 10, kb = (idx3 >> 6) & 15;
        n = tl * 16 + ln;
        int ka = kb * 32 + q * 8;                   // 0..511
        col = (ka < 256) ? ((ka >> 6) * SLOT + 256 + (ka & 63))  // a-slot cols
                         : (1024 + ka);                          // o cols 1280..
    }
    const float* src = W + (size_t)n * CONCAT + col;
    short4v s0, s1;
    s0.x = f2bf(src[0]); s0.y = f2bf(src[1]); s0.z = f2bf(src[2]); s0.w = f2bf(src[3]);
    s1.x = f2bf(src[4]); s1.y = f2bf(src[5]); s1.z = f2bf(src[6]); s1.w = f2bf(src[7]);
    short* dst = Wb + (size_t)idx * 8;
    *(short4v*)dst = s0;
    *(short4v*)(dst + 4) = s1;
}

// Parallel precompute: u = W_ao * [a_hist | o] + b for ALL 65536 tokens, written
// into out (sequential kernel reads u then overwrites with z in-place).
__global__ __launch_bounds__(256) void ugemm_kernel(
    const float* __restrict__ o,    // (B,T,P,256)
    const float* __restrict__ act,  // (B,T,P,64)
    const float* __restrict__ bias, // (256)
    const short* __restrict__ Wb,   // tap secs + Wao
    float* __restrict__ out)        // (B,T,P,256) <- u
{
    __shared__ short xp[64 * XROW];   // 66560 B

    const int tid = threadIdx.x;
    const int wg  = blockIdx.x;       // b = wg>>6, t = wg&63
    const int b   = wg >> 6, t = wg & 63;
    const size_t tau0 = (size_t)wg * 64;

#pragma unroll
    for (int h = 0; h < 4; ++h) {
        int tp = t - 4 + h;
        const float* ap = act + (((size_t)b * 64 + tp) * 64) * 64;
        for (int f = tid; f < 1024; f += 256) {
            int p = f >> 4, c4 = (f & 15) << 2;
            short4v s;
            if (tp >= 0) {
                float4v v = *(const float4v*)(ap + p * 64 + c4);
                s.x = f2bf(v.x); s.y = f2bf(v.y); s.z = f2bf(v.z); s.w = f2bf(v.w);
            } else { s.x = 0; s.y = 0; s.z = 0; s.w = 0; }
            *(short4v*)&xp[p * XROW + h * 64 + c4] = s;
        }
    }
    {
        const float* op = o + tau0 * 256;
        for (int f = tid; f < 4096; f += 256) {
            int p = f >> 6, c4 = (f & 63) << 2;
            float4v v = *(const float4v*)(op + p * 256 + c4);
            short4v s;
            s.x = f2bf(v.x); s.y = f2bf(v.y); s.z = f2bf(v.z); s.w = f2bf(v.w);
            *(short4v*)&xp[p * XROW + 256 + c4] = s;
        }
    }
    __syncthreads();

    const int wv = tid >> 6, lane = tid & 63, q = lane >> 4, ln = lane & 15;
    const short* wao = Wb + 262144;

    float4v acc[4][4];
#pragma unroll
    for (int m = 0; m < 4; ++m)
#pragma unroll
        for (int i = 0; i < 4; ++i)
            acc[m][i] = (float4v){0.f, 0.f, 0.f, 0.f};

#pragma unroll
    for (int kb = 0; kb < 16; ++kb) {
        bf16x8 bf[4];
#pragma unroll
        for (int i = 0; i < 4; ++i)
            bf[i] = *(const bf16x8*)(wao + (((size_t)(4 * wv + i) * 16 + kb) * 64 + lane) * 8);
#pragma unroll
        for (int m = 0; m < 4; ++m) {
            bf16x8 af = *(const bf16x8*)&xp[(m * 16 + ln) * XROW + kb * 32 + q * 8];
#pragma unroll
            for (int i = 0; i < 4; ++i)
                acc[m][i] = __builtin_amdgcn_mfma_f32_16x16x32_bf16(af, bf[i], acc[m][i], 0, 0, 0);
        }
    }

#pragma unroll
    for (int i = 0; i < 4; ++i) {
        float bv = bias[(4 * wv + i) * 16 + ln];
#pragma unroll
        for (int m = 0; m < 4; ++m)
#pragma unroll
            for (int r = 0; r < 4; ++r)
                out[(tau0 + m * 16 + q * 4 + r) * 256 + (4 * wv + i) * 16 + ln] = acc[m][i][r] + bv;
    }
}

// Sequential kernel, tap-pipelined across 4 CUs per team.
// 256 WGs x 1024 thr: team = blk&63 (16 seqs), role = blk>>6 (0=front/tap1, 1..3=taps 2..4).
// Each WG holds its 128KB tap matrix A_h in VGPRs (32/wave) -> ZERO per-step W traffic.
// Tap h computes P_h(t) = A_h z(t-h) (+u(t) for h=4) with h-1 steps of slack, publishes
// via a depth-4 f32 ring + flag (agent-scope atomics). Front: z(t) = A_1 z(t-1) [LDS-local]
// + P_2 + P_3 + P_4; stores z to out (agent atomics) + own LDS history; publishes z-flag.
// Flags: fl[0]=z done count; fl[1..3]=P_{2..4} done count. Depth-4 rings are race-free:
// tap-h at step t waited fl[0] >= t-h+1 => front finished t-h >= t-4+1 => slot t&3 consumed.
// All 256 WGs co-resident (LDS >80KB forces 1 WG/CU; grid == CU count) -> no deadlock.
__global__ __launch_bounds__(1024, 4) void hist_kernel(
    const short* __restrict__ Wpk,
    unsigned* __restrict__ flags,
    float* __restrict__ pring,
    float* out)
{
    __shared__ short lds[45056];   // 90112 B: forces 1 WG/CU (co-residency guarantee)

    const int tid  = threadIdx.x;
    const int wave = tid >> 6;
    const int lane = tid & 63;
    const int q    = lane >> 4;
    const int ln   = lane & 15;
    const int team = blockIdx.x & 63;
    const int role = blockIdx.x >> 6;          // 0..3
    const int bb   = team >> 2;
    const int p0   = (team & 3) << 4;
    unsigned* fl = flags + team * 16;
    float* outb = out + (((size_t)bb * 64) * 64 + p0) * 256;
    const int n = (wave << 4) + ln;

    // resident tap matrix: wave holds N-tile 'wave' x K=256 (8 frags = 32 VGPR)
    bf16x8 wres[8];
    {
        const short* wp = Wpk + ((size_t)role << 16) + ((size_t)(wave * 8) * 64 + lane) * 8;
#pragma unroll
        for (int kb = 0; kb < 8; ++kb)
            wres[kb] = *(const bf16x8*)(wp + kb * 512);
    }

    if (role == 0) {
        // ---------------- FRONT: tap1 + partial-sum + epilogue ----------------
        // LDS z-history: [16 rows][2 slots x 256 + 8 pad]; z(j) in slot j&1
        for (int i = tid; i < 4160; i += 1024) ((float*)lds)[i] = 0.f;
        __syncthreads();
        const int arow = ln * 520 + (q << 3);
        for (int t = 0; t < TT; ++t) {
            const int sb = ((t + 1) & 1) << 8;       // slot of z(t-1)
            float4v a0 = {0.f, 0.f, 0.f, 0.f}, a1 = a0;
#pragma unroll
            for (int kb = 0; kb < 8; kb += 2) {
                bf16x8 f0 = *(const bf16x8*)&lds[arow + sb + kb * 32];
                bf16x8 f1 = *(const bf16x8*)&lds[arow + sb + kb * 32 + 32];
                a0 = __builtin_amdgcn_mfma_f32_16x16x32_bf16(f0, wres[kb],     a0, 0, 0, 0);
                a1 = __builtin_amdgcn_mfma_f32_16x16x32_bf16(f1, wres[kb + 1], a1, 0, 0, 0);
            }
            if (tid == 0) {
                const unsigned need = (unsigned)(t + 1);
                while (AL(&fl[1]) < need) SPIN_PAUSE;
                while (AL(&fl[2]) < need) SPIN_PAUSE;
                while (AL(&fl[3]) < need) SPIN_PAUSE;
            }
            __syncthreads();
            const size_t rs = (size_t)(team * 4 + (t & 3)) * 4096 + (size_t)(tid << 2);
            float4v P2, P3, P4;
#pragma unroll
            for (int r = 0; r < 4; ++r) {
                P2[r] = AL(&pring[rs + r]);
                P3[r] = AL(&pring[rs + 1048576 + r]);
                P4[r] = AL(&pring[rs + 2097152 + r]);
            }
            float4v z = (a0 + a1) + ((P2 + P3) + P4);
            float* outp = outb + (size_t)t * 16384;
            const int hw = (t & 1) << 8;
#pragma unroll
            for (int r = 0; r < 4; ++r) {
                const int m = (q << 2) + r;
                AS(&outp[m * 256 + n], z[r]);            // z -> out (device-visible)
                lds[m * 520 + hw + n] = f2bf(z[r]);      // own next-step history
            }
            __syncthreads();   // drains stores (vmcnt 0) + orders LDS for next step
            if (tid == 0) AS(&fl[0], (unsigned)(t + 1));
        }
    } else {
        // ---------------- TAP h = role+1: P_h(t) = A_h z(t-h) (+u for h=4) ----------------
        const int h = role + 1;
        for (int i = tid; i < 2112; i += 1024) ((float*)lds)[i] = 0.f;   // [16][264] staging
        const int arow = ln * 264 + (q << 3);
        float* ringp = pring + (size_t)((role - 1) * 256 + team * 4) * 4096;
        __syncthreads();
        for (int t = 0; t < TT; ++t) {
            if (tid == 0 && t >= h) {
                const unsigned need = (unsigned)(t - h + 1);
                while (AL(&fl[0]) < need) SPIN_PAUSE;
            }
            __syncthreads();
            float uu0 = 0.f, uu1 = 0.f, uu2 = 0.f, uu3 = 0.f;
            if (h == 4) {      // read u(t) BEFORE front overwrites (front is >=3 steps behind)
                const float* up = outb + (size_t)t * 16384;
                uu0 = AL(&up[((q << 2) + 0) * 256 + n]);
                uu1 = AL(&up[((q << 2) + 1) * 256 + n]);
                uu2 = AL(&up[((q << 2) + 2) * 256 + n]);
                uu3 = AL(&up[((q << 2) + 3) * 256 + n]);
            }
            if (t >= h) {      // stage z(t-h) -> bf16 LDS
                const float* zp = outb + (size_t)(t - h) * 16384;
                const int row = tid >> 6, c4 = (tid & 63) << 2;
                float z0 = AL(&zp[row * 256 + c4]);
                float z1 = AL(&zp[row * 256 + c4 + 1]);
                float z2 = AL(&zp[row * 256 + c4 + 2]);
                float z3 = AL(&zp[row * 256 + c4 + 3]);
                short4v s;
                s.x = f2bf(z0); s.y = f2bf(z1); s.z = f2bf(z2); s.w = f2bf(z3);
                *(short4v*)&lds[row * 264 + c4] = s;
            }
            __syncthreads();
            float4v a0 = {0.f, 0.f, 0.f, 0.f}, a1 = a0;
#pragma unroll
            for (int kb = 0; kb < 8; kb += 2) {
                bf16x8 f0 = *(const bf16x8*)&lds[arow + kb * 32];
                bf16x8 f1 = *(const bf16x8*)&lds[arow + kb * 32 + 32];
                a0 = __builtin_amdgcn_mfma_f32_16x16x32_bf16(f0, wres[kb],     a0, 0, 0, 0);
                a1 = __builtin_amdgcn_mfma_f32_16x16x32_bf16(f1, wres[kb + 1], a1, 0, 0, 0);
            }
            float4v P = a0 + a1;
            P[0] += uu0; P[1] += uu1; P[2] += uu2; P[3] += uu3;
            float* pp = ringp + (size_t)(t & 3) * 4096 + (size_t)(tid << 2);
#pragma unroll
            for (int r = 0; r < 4; ++r) AS(&pp[r], P[r]);
            __syncthreads();   // drain P stores before publishing
            if (tid == 0) AS(&fl[role], (unsigned)(t + 1));
        }
    }
}

extern "C" void kernel_launch(void* const* d_in, const int* in_sizes, int n_in,
                              void* d_out, int out_size, void* d_ws, size_t ws_size,
                              hipStream_t stream) {
    const float* o  = (const float*)d_in[0];
    const float* a  = (const float*)d_in[1];
    const float* W  = (const float*)d_in[2];
    const float* b  = (const float*)d_in[3];
    short*    Wb    = (short*)d_ws;                               // 768 KB packed W
    unsigned* flags = (unsigned*)((char*)d_ws + 786432);          // 4 KB flags
    float*    pring = (float*)((char*)d_ws + 790528);             // 12.6 MB partial rings

    hipLaunchKernelGGL(wprep_kernel, dim3(192), dim3(256), 0, stream, W, Wb, flags);
    hipLaunchKernelGGL(ugemm_kernel, dim3(1024), dim3(256), 0, stream,
                       o, a, b, Wb, (float*)d_out);
    hipLaunchKernelGGL(hist_kernel, dim3(256), dim3(1024), 0, stream,
                       Wb, flags, pring, (float*)d_out);
}